// Round 1
// baseline (393.380 us; speedup 1.0000x reference)
//
#include <hip/hip_runtime.h>
#include <math.h>

#define D 768
#define DOUT 384
#define LSEQ 512
#define BATCH 4
#define KTOP 51
#define EPS 1e-5f

// ---------------------------------------------------------------------------
// Top-K selection: one block per attention row. Rank-based selection exactly
// matches jax.lax.top_k tie rule (lower index wins); only the SET of indices
// matters downstream (softmax over k + sum over k are order-invariant).
// ---------------------------------------------------------------------------
__global__ __launch_bounds__(256) void topk_kernel(const float* __restrict__ attn,
                                                   int* __restrict__ tk_idx,
                                                   float* __restrict__ tk_val) {
    const int row = blockIdx.x;                 // b*L + l
    const float* a = attn + (size_t)row * LSEQ;
    __shared__ float vals[LSEQ];
    __shared__ int cnt;
    const int tid = threadIdx.x;
    vals[tid] = a[tid];
    vals[tid + 256] = a[tid + 256];
    if (tid == 0) cnt = 0;
    __syncthreads();
#pragma unroll
    for (int e0 = 0; e0 < 2; ++e0) {
        const int e = tid + e0 * 256;
        const float v = vals[e];
        int rank = 0;
#pragma unroll 8
        for (int j = 0; j < LSEQ; ++j) {
            const float u = vals[j];
            rank += (u > v) || (u == v && j < e);
        }
        if (rank < KTOP) {
            const int slot = atomicAdd(&cnt, 1);
            tk_idx[row * KTOP + slot] = e;
            tk_val[row * KTOP + slot] = v;
        }
    }
}

// ---------------------------------------------------------------------------
// fp32 tiled GEMM: C = A(2048xD) @ W(DxD) + bias, two weight sets via blockIdx.z
// BM=BN=64, BK=16, 256 threads, 4x4 micro-tile per thread.
// ---------------------------------------------------------------------------
__global__ __launch_bounds__(256) void gemm_kernel(const float* __restrict__ A,
                                                   const float* __restrict__ W0,
                                                   const float* __restrict__ b0,
                                                   float* __restrict__ C0,
                                                   const float* __restrict__ W1,
                                                   const float* __restrict__ b1,
                                                   float* __restrict__ C1) {
    const float* W = blockIdx.z ? W1 : W0;
    const float* bias = blockIdx.z ? b1 : b0;
    float* C = blockIdx.z ? C1 : C0;

    __shared__ float As[16][68];   // transposed A tile, padded
    __shared__ float Bs[16][68];

    const int tid = threadIdx.x;
    const int tr = tid >> 4, tc = tid & 15;       // 16x16 thread grid
    const int ar = tid >> 2, ac4 = (tid & 3) * 4; // A tile load: 64 rows x 4 float4
    const int br = tid >> 4, bc4 = (tid & 15) * 4;// B tile load: 16 rows x 16 float4
    const int rowBase = blockIdx.y * 64;
    const int colBase = blockIdx.x * 64;

    float acc[4][4] = {};

    for (int kk = 0; kk < D; kk += 16) {
        const float4 av = *(const float4*)(A + (size_t)(rowBase + ar) * D + kk + ac4);
        const float4 bv = *(const float4*)(W + (size_t)(kk + br) * D + colBase + bc4);
        As[ac4 + 0][ar] = av.x;
        As[ac4 + 1][ar] = av.y;
        As[ac4 + 2][ar] = av.z;
        As[ac4 + 3][ar] = av.w;
        *(float4*)&Bs[br][bc4] = bv;
        __syncthreads();
#pragma unroll
        for (int k = 0; k < 16; ++k) {
            const float4 a4 = *(const float4*)&As[k][tr * 4];
            const float4 b4 = *(const float4*)&Bs[k][tc * 4];
            acc[0][0] += a4.x * b4.x; acc[0][1] += a4.x * b4.y; acc[0][2] += a4.x * b4.z; acc[0][3] += a4.x * b4.w;
            acc[1][0] += a4.y * b4.x; acc[1][1] += a4.y * b4.y; acc[1][2] += a4.y * b4.z; acc[1][3] += a4.y * b4.w;
            acc[2][0] += a4.z * b4.x; acc[2][1] += a4.z * b4.y; acc[2][2] += a4.z * b4.z; acc[2][3] += a4.z * b4.w;
            acc[3][0] += a4.w * b4.x; acc[3][1] += a4.w * b4.y; acc[3][2] += a4.w * b4.z; acc[3][3] += a4.w * b4.w;
        }
        __syncthreads();
    }

#pragma unroll
    for (int i = 0; i < 4; ++i) {
        const int row = rowBase + tr * 4 + i;
#pragma unroll
        for (int j = 0; j < 4; ++j) {
            const int col = colBase + tc * 4 + j;
            C[(size_t)row * D + col] = acc[i][j] + bias[col];
        }
    }
}

// ---------------------------------------------------------------------------
// GAT: scores -> softmax over K -> aggregate -> residual + leaky -> gate dot.
// One block of 256 threads (4 waves) per (b,l).
// ---------------------------------------------------------------------------
__global__ __launch_bounds__(256) void gat_kernel(const float* __restrict__ feat_src,
                                                  const float* __restrict__ feat_dst,
                                                  const float* __restrict__ attn_vec,
                                                  const float* __restrict__ hidden,
                                                  const float* __restrict__ gat_bias,
                                                  const float* __restrict__ gate_W,
                                                  const float* __restrict__ gate_b,
                                                  const int* __restrict__ tk_idx,
                                                  const float* __restrict__ tk_val,
                                                  float* __restrict__ h_out,
                                                  float* __restrict__ gate_out) {
    const int row = blockIdx.x;     // b*L + l
    const int b = row >> 9;
    const int tid = threadIdx.x;
    const int lane = tid & 63;
    const int wave = tid >> 6;

    __shared__ float fd[D];
    __shared__ float av[D];
    __shared__ float sc[KTOP];
    __shared__ int kid[KTOP];
    __shared__ float red[256];

    for (int d = tid; d < D; d += 256) {
        fd[d] = feat_dst[(size_t)row * D + d];
        av[d] = attn_vec[d];
    }
    if (tid < KTOP) kid[tid] = tk_idx[row * KTOP + tid];
    __syncthreads();

    // scores: wave w handles k = w, w+4, ...
    for (int k = wave; k < KTOP; k += 4) {
        const float* g = feat_src + ((size_t)(b << 9) + kid[k]) * D;
        float s = 0.f;
        for (int d = lane; d < D; d += 64) {
            float x = g[d] + fd[d];
            x = x > 0.f ? x : 0.2f * x;
            s += x * av[d];
        }
#pragma unroll
        for (int off = 32; off > 0; off >>= 1) s += __shfl_down(s, off);
        if (lane == 0) {
            const float v = tk_val[row * KTOP + k];
            sc[k] = (v > 0.f) ? s : -1e9f;
        }
    }
    __syncthreads();

    // softmax over KTOP (wave 0)
    if (wave == 0) {
        float s = (lane < KTOP) ? sc[lane] : -3.0e38f;
        float m = s;
#pragma unroll
        for (int off = 32; off > 0; off >>= 1) m = fmaxf(m, __shfl_xor(m, off));
        float e = (lane < KTOP) ? __expf(s - m) : 0.f;
        float sum = e;
#pragma unroll
        for (int off = 32; off > 0; off >>= 1) sum += __shfl_xor(sum, off);
        if (lane < KTOP) sc[lane] = e / sum;
    }
    __syncthreads();

    // aggregation: thread owns dims tid, tid+256, tid+512
    float gpart = 0.f;
    for (int d = tid; d < D; d += 256) {
        float acc = 0.f;
        for (int k = 0; k < KTOP; ++k) {
            const float* g = feat_src + ((size_t)(b << 9) + kid[k]) * D;
            acc += sc[k] * g[d];
        }
        float hv = acc + hidden[(size_t)row * D + d] + gat_bias[d];
        hv = hv > 0.f ? hv : 0.01f * hv;
        h_out[(size_t)row * D + d] = hv;
        gpart += hv * gate_W[d];
    }
    red[tid] = gpart;
    __syncthreads();
    for (int s = 128; s > 0; s >>= 1) {
        if (tid < s) red[tid] += red[tid + s];
        __syncthreads();
    }
    if (tid == 0) gate_out[row] = red[0] + gate_b[0];
}

// ---------------------------------------------------------------------------
// Final: gate softmax over L, pooling, relu+LN(768), fc(768x384), LN(384).
// One block per batch.
// ---------------------------------------------------------------------------
__global__ __launch_bounds__(256) void final_kernel(const float* __restrict__ h,
                                                    const float* __restrict__ gate,
                                                    const float* __restrict__ ln_g,
                                                    const float* __restrict__ ln_b,
                                                    const float* __restrict__ fc_W,
                                                    const float* __restrict__ fc_b,
                                                    const float* __restrict__ ln2_g,
                                                    const float* __restrict__ ln2_b,
                                                    float* __restrict__ out) {
    const int b = blockIdx.x;
    const int tid = threadIdx.x;
    __shared__ float p[LSEQ];
    __shared__ float red[256];
    __shared__ float y[D];
    __shared__ float z[DOUT];

    // softmax over gate (length 512)
    const float g0 = gate[b * LSEQ + tid];
    const float g1 = gate[b * LSEQ + tid + 256];
    red[tid] = fmaxf(g0, g1);
    __syncthreads();
    for (int s = 128; s > 0; s >>= 1) { if (tid < s) red[tid] = fmaxf(red[tid], red[tid + s]); __syncthreads(); }
    const float m = red[0];
    __syncthreads();
    const float e0 = __expf(g0 - m), e1 = __expf(g1 - m);
    red[tid] = e0 + e1;
    __syncthreads();
    for (int s = 128; s > 0; s >>= 1) { if (tid < s) red[tid] += red[tid + s]; __syncthreads(); }
    const float inv = 1.f / red[0];
    __syncthreads();
    p[tid] = e0 * inv;
    p[tid + 256] = e1 * inv;
    __syncthreads();

    // pooled: thread owns dims tid, tid+256, tid+512
    float pool[3] = {0.f, 0.f, 0.f};
    for (int l = 0; l < LSEQ; ++l) {
        const float pl = p[l];
        const float* hr = h + (size_t)(b * LSEQ + l) * D;
#pragma unroll
        for (int i = 0; i < 3; ++i) pool[i] += pl * hr[tid + i * 256];
    }
#pragma unroll
    for (int i = 0; i < 3; ++i) pool[i] = fmaxf(pool[i], 0.f);   // relu

    // LN over D (two-pass)
    red[tid] = pool[0] + pool[1] + pool[2];
    __syncthreads();
    for (int s = 128; s > 0; s >>= 1) { if (tid < s) red[tid] += red[tid + s]; __syncthreads(); }
    const float mu = red[0] / (float)D;
    __syncthreads();
    float vs = 0.f;
#pragma unroll
    for (int i = 0; i < 3; ++i) { const float dd = pool[i] - mu; vs += dd * dd; }
    red[tid] = vs;
    __syncthreads();
    for (int s = 128; s > 0; s >>= 1) { if (tid < s) red[tid] += red[tid + s]; __syncthreads(); }
    const float rstd = rsqrtf(red[0] / (float)D + EPS);
    __syncthreads();
#pragma unroll
    for (int i = 0; i < 3; ++i) {
        const int d = tid + i * 256;
        y[d] = (pool[i] - mu) * rstd * ln_g[d] + ln_b[d];
    }
    __syncthreads();

    // matvec: z = y @ fc_W + fc_b  (768 x 384)
    for (int j = tid; j < DOUT; j += 256) {
        float acc = fc_b[j];
        for (int d = 0; d < D; ++d) acc += y[d] * fc_W[(size_t)d * DOUT + j];
        z[j] = acc;
    }
    __syncthreads();

    // LN over DOUT
    const float c1valid = (tid + 256 < DOUT) ? 1.f : 0.f;
    red[tid] = z[tid] + c1valid * ((tid + 256 < DOUT) ? z[tid + 256] : 0.f);
    __syncthreads();
    for (int s = 128; s > 0; s >>= 1) { if (tid < s) red[tid] += red[tid + s]; __syncthreads(); }
    const float mu2 = red[0] / (float)DOUT;
    __syncthreads();
    const float d0 = z[tid] - mu2;
    const float d1 = (tid + 256 < DOUT) ? (z[tid + 256] - mu2) : 0.f;
    red[tid] = d0 * d0 + d1 * d1;
    __syncthreads();
    for (int s = 128; s > 0; s >>= 1) { if (tid < s) red[tid] += red[tid + s]; __syncthreads(); }
    const float rstd2 = rsqrtf(red[0] / (float)DOUT + EPS);

    out[b * DOUT + tid] = (z[tid] - mu2) * rstd2 * ln2_g[tid] + ln2_b[tid];
    if (tid + 256 < DOUT) {
        const int j = tid + 256;
        out[b * DOUT + j] = (z[j] - mu2) * rstd2 * ln2_g[j] + ln2_b[j];
    }
}

extern "C" void kernel_launch(void* const* d_in, const int* in_sizes, int n_in,
                              void* d_out, int out_size, void* d_ws, size_t ws_size,
                              hipStream_t stream) {
    const float* hidden   = (const float*)d_in[0];   // (4,512,768)
    const float* attention= (const float*)d_in[1];   // (4,512,512)
    const float* W_src    = (const float*)d_in[2];
    const float* b_src    = (const float*)d_in[3];
    const float* W_dst    = (const float*)d_in[4];
    const float* b_dst    = (const float*)d_in[5];
    const float* attn_vec = (const float*)d_in[6];
    const float* gat_bias = (const float*)d_in[7];
    const float* gate_W   = (const float*)d_in[8];
    const float* gate_b   = (const float*)d_in[9];
    const float* ln_g     = (const float*)d_in[10];
    const float* ln_b     = (const float*)d_in[11];
    const float* fc_W     = (const float*)d_in[12];
    const float* fc_b     = (const float*)d_in[13];
    const float* ln2_g    = (const float*)d_in[14];
    const float* ln2_b    = (const float*)d_in[15];
    float* out = (float*)d_out;

    const int M = BATCH * LSEQ;           // 2048
    float* feat_src = (float*)d_ws;                       // M*D
    float* feat_dst = feat_src + (size_t)M * D;           // M*D
    float* h        = feat_dst + (size_t)M * D;           // M*D
    float* gate     = h + (size_t)M * D;                  // M
    float* tk_val   = gate + M;                           // M*KTOP
    int*   tk_idx   = (int*)(tk_val + (size_t)M * KTOP);  // M*KTOP

    hipLaunchKernelGGL(topk_kernel, dim3(M), dim3(256), 0, stream,
                       attention, tk_idx, tk_val);
    hipLaunchKernelGGL(gemm_kernel, dim3(D / 64, M / 64, 2), dim3(256), 0, stream,
                       hidden, W_src, b_src, feat_src, W_dst, b_dst, feat_dst);
    hipLaunchKernelGGL(gat_kernel, dim3(M), dim3(256), 0, stream,
                       feat_src, feat_dst, attn_vec, hidden, gat_bias,
                       gate_W, gate_b, tk_idx, tk_val, h, gate);
    hipLaunchKernelGGL(final_kernel, dim3(BATCH), dim3(256), 0, stream,
                       h, gate, ln_g, ln_b, fc_W, fc_b, ln2_g, ln2_b, out);
}

// Round 2
// 320.435 us; speedup vs baseline: 1.2276x; 1.2276x over previous
//
#include <hip/hip_runtime.h>
#include <math.h>

#define D 768
#define DOUT 384
#define LSEQ 512
#define BATCH 4
#define KTOP 51
#define EPS 1e-5f

// ---------------------------------------------------------------------------
// Top-K selection: one block per attention row. Rank-based selection exactly
// matches jax.lax.top_k tie rule (lower index wins); only the SET of indices
// matters downstream (softmax over k + sum over k are order-invariant).
// ---------------------------------------------------------------------------
__global__ __launch_bounds__(256) void topk_kernel(const float* __restrict__ attn,
                                                   int* __restrict__ tk_idx,
                                                   float* __restrict__ tk_val) {
    const int row = blockIdx.x;                 // b*L + l
    const float* a = attn + (size_t)row * LSEQ;
    __shared__ float vals[LSEQ];
    __shared__ int cnt;
    const int tid = threadIdx.x;
    vals[tid] = a[tid];
    vals[tid + 256] = a[tid + 256];
    if (tid == 0) cnt = 0;
    __syncthreads();
#pragma unroll
    for (int e0 = 0; e0 < 2; ++e0) {
        const int e = tid + e0 * 256;
        const float v = vals[e];
        int rank = 0;
#pragma unroll 8
        for (int j = 0; j < LSEQ; ++j) {
            const float u = vals[j];
            rank += (u > v) || (u == v && j < e);
        }
        if (rank < KTOP) {
            const int slot = atomicAdd(&cnt, 1);
            tk_idx[row * KTOP + slot] = e;
            tk_val[row * KTOP + slot] = v;
        }
    }
}

// ---------------------------------------------------------------------------
// fp32 tiled GEMM: C = A(2048xD) @ W(DxD) + bias, two weight sets via blockIdx.z
// BM=BN=64, BK=16, 256 threads, 4x4 micro-tile per thread.
// ---------------------------------------------------------------------------
__global__ __launch_bounds__(256) void gemm_kernel(const float* __restrict__ A,
                                                   const float* __restrict__ W0,
                                                   const float* __restrict__ b0,
                                                   float* __restrict__ C0,
                                                   const float* __restrict__ W1,
                                                   const float* __restrict__ b1,
                                                   float* __restrict__ C1) {
    const float* W = blockIdx.z ? W1 : W0;
    const float* bias = blockIdx.z ? b1 : b0;
    float* C = blockIdx.z ? C1 : C0;

    __shared__ float As[16][68];   // transposed A tile, padded
    __shared__ float Bs[16][68];

    const int tid = threadIdx.x;
    const int tr = tid >> 4, tc = tid & 15;       // 16x16 thread grid
    const int ar = tid >> 2, ac4 = (tid & 3) * 4; // A tile load: 64 rows x 4 float4
    const int br = tid >> 4, bc4 = (tid & 15) * 4;// B tile load: 16 rows x 16 float4
    const int rowBase = blockIdx.y * 64;
    const int colBase = blockIdx.x * 64;

    float acc[4][4] = {};

    for (int kk = 0; kk < D; kk += 16) {
        const float4 av = *(const float4*)(A + (size_t)(rowBase + ar) * D + kk + ac4);
        const float4 bv = *(const float4*)(W + (size_t)(kk + br) * D + colBase + bc4);
        As[ac4 + 0][ar] = av.x;
        As[ac4 + 1][ar] = av.y;
        As[ac4 + 2][ar] = av.z;
        As[ac4 + 3][ar] = av.w;
        *(float4*)&Bs[br][bc4] = bv;
        __syncthreads();
#pragma unroll
        for (int k = 0; k < 16; ++k) {
            const float4 a4 = *(const float4*)&As[k][tr * 4];
            const float4 b4 = *(const float4*)&Bs[k][tc * 4];
            acc[0][0] += a4.x * b4.x; acc[0][1] += a4.x * b4.y; acc[0][2] += a4.x * b4.z; acc[0][3] += a4.x * b4.w;
            acc[1][0] += a4.y * b4.x; acc[1][1] += a4.y * b4.y; acc[1][2] += a4.y * b4.z; acc[1][3] += a4.y * b4.w;
            acc[2][0] += a4.z * b4.x; acc[2][1] += a4.z * b4.y; acc[2][2] += a4.z * b4.z; acc[2][3] += a4.z * b4.w;
            acc[3][0] += a4.w * b4.x; acc[3][1] += a4.w * b4.y; acc[3][2] += a4.w * b4.z; acc[3][3] += a4.w * b4.w;
        }
        __syncthreads();
    }

#pragma unroll
    for (int i = 0; i < 4; ++i) {
        const int row = rowBase + tr * 4 + i;
#pragma unroll
        for (int j = 0; j < 4; ++j) {
            const int col = colBase + tc * 4 + j;
            C[(size_t)row * D + col] = acc[i][j] + bias[col];
        }
    }
}

// ---------------------------------------------------------------------------
// GAT: scores -> softmax over K -> aggregate -> residual + leaky -> gate dot.
// One block of 256 threads (4 waves) per (b,l).
// ---------------------------------------------------------------------------
__global__ __launch_bounds__(256) void gat_kernel(const float* __restrict__ feat_src,
                                                  const float* __restrict__ feat_dst,
                                                  const float* __restrict__ attn_vec,
                                                  const float* __restrict__ hidden,
                                                  const float* __restrict__ gat_bias,
                                                  const float* __restrict__ gate_W,
                                                  const float* __restrict__ gate_b,
                                                  const int* __restrict__ tk_idx,
                                                  const float* __restrict__ tk_val,
                                                  float* __restrict__ h_out,
                                                  float* __restrict__ gate_out) {
    const int row = blockIdx.x;     // b*L + l
    const int b = row >> 9;
    const int tid = threadIdx.x;
    const int lane = tid & 63;
    const int wave = tid >> 6;

    __shared__ float fd[D];
    __shared__ float av[D];
    __shared__ float sc[KTOP];
    __shared__ int kid[KTOP];
    __shared__ float red[256];

    for (int d = tid; d < D; d += 256) {
        fd[d] = feat_dst[(size_t)row * D + d];
        av[d] = attn_vec[d];
    }
    if (tid < KTOP) kid[tid] = tk_idx[row * KTOP + tid];
    __syncthreads();

    // scores: wave w handles k = w, w+4, ...
    for (int k = wave; k < KTOP; k += 4) {
        const float* g = feat_src + ((size_t)(b << 9) + kid[k]) * D;
        float s = 0.f;
        for (int d = lane; d < D; d += 64) {
            float x = g[d] + fd[d];
            x = x > 0.f ? x : 0.2f * x;
            s += x * av[d];
        }
#pragma unroll
        for (int off = 32; off > 0; off >>= 1) s += __shfl_down(s, off);
        if (lane == 0) {
            const float v = tk_val[row * KTOP + k];
            sc[k] = (v > 0.f) ? s : -1e9f;
        }
    }
    __syncthreads();

    // softmax over KTOP (wave 0)
    if (wave == 0) {
        float s = (lane < KTOP) ? sc[lane] : -3.0e38f;
        float m = s;
#pragma unroll
        for (int off = 32; off > 0; off >>= 1) m = fmaxf(m, __shfl_xor(m, off));
        float e = (lane < KTOP) ? __expf(s - m) : 0.f;
        float sum = e;
#pragma unroll
        for (int off = 32; off > 0; off >>= 1) sum += __shfl_xor(sum, off);
        if (lane < KTOP) sc[lane] = e / sum;
    }
    __syncthreads();

    // aggregation: thread owns dims tid, tid+256, tid+512
    float gpart = 0.f;
    for (int d = tid; d < D; d += 256) {
        float acc = 0.f;
        for (int k = 0; k < KTOP; ++k) {
            const float* g = feat_src + ((size_t)(b << 9) + kid[k]) * D;
            acc += sc[k] * g[d];
        }
        float hv = acc + hidden[(size_t)row * D + d] + gat_bias[d];
        hv = hv > 0.f ? hv : 0.01f * hv;
        h_out[(size_t)row * D + d] = hv;
        gpart += hv * gate_W[d];
    }
    red[tid] = gpart;
    __syncthreads();
    for (int s = 128; s > 0; s >>= 1) {
        if (tid < s) red[tid] += red[tid + s];
        __syncthreads();
    }
    if (tid == 0) gate_out[row] = red[0] + gate_b[0];
}

// ---------------------------------------------------------------------------
// Final stage, split for parallelism.
// K_gate: per-batch gate softmax -> p; also zero pooled/z accumulators.
// ---------------------------------------------------------------------------
__global__ __launch_bounds__(256) void gatesm_kernel(const float* __restrict__ gate,
                                                     float* __restrict__ p,
                                                     float* __restrict__ pooled,
                                                     float* __restrict__ z) {
    const int b = blockIdx.x;
    const int tid = threadIdx.x;
    __shared__ float red[256];

    const float g0 = gate[b * LSEQ + tid];
    const float g1 = gate[b * LSEQ + tid + 256];
    red[tid] = fmaxf(g0, g1);
    __syncthreads();
    for (int s = 128; s > 0; s >>= 1) { if (tid < s) red[tid] = fmaxf(red[tid], red[tid + s]); __syncthreads(); }
    const float m = red[0];
    __syncthreads();
    const float e0 = __expf(g0 - m), e1 = __expf(g1 - m);
    red[tid] = e0 + e1;
    __syncthreads();
    for (int s = 128; s > 0; s >>= 1) { if (tid < s) red[tid] += red[tid + s]; __syncthreads(); }
    const float inv = 1.f / red[0];
    p[b * LSEQ + tid] = e0 * inv;
    p[b * LSEQ + tid + 256] = e1 * inv;

    // zero accumulators for this batch
    for (int d = tid; d < D; d += 256) pooled[b * D + d] = 0.f;
    if (tid < 128) { z[b * DOUT + tid] = 0.f; z[b * DOUT + tid + 128] = 0.f; z[b * DOUT + tid + 256] = 0.f; }
}

// ---------------------------------------------------------------------------
// K_pool: partial pooled[b][d] = sum_l p[b][l]*h[b][l][d] over a 64-l chunk.
// grid (D/256, L/64, B), block 256. atomicAdd into pooled.
// ---------------------------------------------------------------------------
__global__ __launch_bounds__(256) void pool_kernel(const float* __restrict__ h,
                                                   const float* __restrict__ p,
                                                   float* __restrict__ pooled) {
    const int b = blockIdx.z;
    const int lbase = blockIdx.y * 64;
    const int d = blockIdx.x * 256 + threadIdx.x;
    const int tid = threadIdx.x;

    __shared__ float ps[64];
    if (tid < 64) ps[tid] = p[b * LSEQ + lbase + tid];
    __syncthreads();

    const float* hb = h + ((size_t)(b * LSEQ + lbase)) * D + d;
    float acc = 0.f;
#pragma unroll 8
    for (int l = 0; l < 64; ++l) {
        acc += ps[l] * hb[(size_t)l * D];
    }
    atomicAdd(&pooled[b * D + d], acc);
}

// ---------------------------------------------------------------------------
// K_ln1: relu + LayerNorm(768) -> y.  grid B, block 256.
// ---------------------------------------------------------------------------
__global__ __launch_bounds__(256) void ln1_kernel(const float* __restrict__ pooled,
                                                  const float* __restrict__ ln_g,
                                                  const float* __restrict__ ln_b,
                                                  float* __restrict__ y) {
    const int b = blockIdx.x;
    const int tid = threadIdx.x;
    __shared__ float red[256];

    float v[3];
#pragma unroll
    for (int i = 0; i < 3; ++i) v[i] = fmaxf(pooled[b * D + tid + i * 256], 0.f);

    red[tid] = v[0] + v[1] + v[2];
    __syncthreads();
    for (int s = 128; s > 0; s >>= 1) { if (tid < s) red[tid] += red[tid + s]; __syncthreads(); }
    const float mu = red[0] / (float)D;
    __syncthreads();
    float vs = 0.f;
#pragma unroll
    for (int i = 0; i < 3; ++i) { const float dd = v[i] - mu; vs += dd * dd; }
    red[tid] = vs;
    __syncthreads();
    for (int s = 128; s > 0; s >>= 1) { if (tid < s) red[tid] += red[tid + s]; __syncthreads(); }
    const float rstd = rsqrtf(red[0] / (float)D + EPS);
#pragma unroll
    for (int i = 0; i < 3; ++i) {
        const int d = tid + i * 256;
        y[b * D + d] = (v[i] - mu) * rstd * ln_g[d] + ln_b[d];
    }
}

// ---------------------------------------------------------------------------
// K_fc: partial z[b][j] += sum_{d in chunk} y[b][d] * fc_W[d][j].
// grid (DOUT/64, D/256, B), block 256 = 4 subs x 64 j.
// ---------------------------------------------------------------------------
__global__ __launch_bounds__(256) void fc_kernel(const float* __restrict__ y,
                                                 const float* __restrict__ fc_W,
                                                 float* __restrict__ z) {
    const int b = blockIdx.z;
    const int dbase = blockIdx.y * 256;
    const int jbase = blockIdx.x * 64;
    const int tid = threadIdx.x;
    const int jt = tid & 63;
    const int sub = tid >> 6;           // 0..3, each covers 64 d's

    __shared__ float ys[256];
    __shared__ float part[4][64];
    ys[tid] = y[b * D + dbase + tid];
    __syncthreads();

    const float* W = fc_W + (size_t)(dbase + sub * 64) * DOUT + jbase + jt;
    const float* yy = ys + sub * 64;
    float acc = 0.f;
#pragma unroll 8
    for (int i = 0; i < 64; ++i) {
        acc += yy[i] * W[(size_t)i * DOUT];
    }
    part[sub][jt] = acc;
    __syncthreads();
    if (sub == 0) {
        const float tot = part[0][jt] + part[1][jt] + part[2][jt] + part[3][jt];
        atomicAdd(&z[b * DOUT + jbase + jt], tot);
    }
}

// ---------------------------------------------------------------------------
// K_ln2: add bias, LayerNorm(384) -> out.  grid B, block 384 (6 waves).
// ---------------------------------------------------------------------------
__global__ __launch_bounds__(384) void ln2_kernel(const float* __restrict__ z,
                                                  const float* __restrict__ fc_b,
                                                  const float* __restrict__ ln2_g,
                                                  const float* __restrict__ ln2_b,
                                                  float* __restrict__ out) {
    const int b = blockIdx.x;
    const int tid = threadIdx.x;
    const int lane = tid & 63;
    const int wave = tid >> 6;
    __shared__ float wred[6];

    const float v = z[b * DOUT + tid] + fc_b[tid];

    float s = v;
#pragma unroll
    for (int off = 32; off > 0; off >>= 1) s += __shfl_xor(s, off);
    if (lane == 0) wred[wave] = s;
    __syncthreads();
    float mu = 0.f;
#pragma unroll
    for (int w = 0; w < 6; ++w) mu += wred[w];
    mu /= (float)DOUT;
    __syncthreads();

    const float dd = v - mu;
    float s2 = dd * dd;
#pragma unroll
    for (int off = 32; off > 0; off >>= 1) s2 += __shfl_xor(s2, off);
    if (lane == 0) wred[wave] = s2;
    __syncthreads();
    float var = 0.f;
#pragma unroll
    for (int w = 0; w < 6; ++w) var += wred[w];
    const float rstd = rsqrtf(var / (float)DOUT + EPS);

    out[b * DOUT + tid] = dd * rstd * ln2_g[tid] + ln2_b[tid];
}

extern "C" void kernel_launch(void* const* d_in, const int* in_sizes, int n_in,
                              void* d_out, int out_size, void* d_ws, size_t ws_size,
                              hipStream_t stream) {
    const float* hidden   = (const float*)d_in[0];   // (4,512,768)
    const float* attention= (const float*)d_in[1];   // (4,512,512)
    const float* W_src    = (const float*)d_in[2];
    const float* b_src    = (const float*)d_in[3];
    const float* W_dst    = (const float*)d_in[4];
    const float* b_dst    = (const float*)d_in[5];
    const float* attn_vec = (const float*)d_in[6];
    const float* gat_bias = (const float*)d_in[7];
    const float* gate_W   = (const float*)d_in[8];
    const float* gate_b   = (const float*)d_in[9];
    const float* ln_g     = (const float*)d_in[10];
    const float* ln_b     = (const float*)d_in[11];
    const float* fc_W     = (const float*)d_in[12];
    const float* fc_b     = (const float*)d_in[13];
    const float* ln2_g    = (const float*)d_in[14];
    const float* ln2_b    = (const float*)d_in[15];
    float* out = (float*)d_out;

    const int M = BATCH * LSEQ;           // 2048
    float* feat_src = (float*)d_ws;                       // M*D
    float* feat_dst = feat_src + (size_t)M * D;           // M*D
    float* h        = feat_dst + (size_t)M * D;           // M*D
    float* gate     = h + (size_t)M * D;                  // M
    float* tk_val   = gate + M;                           // M*KTOP
    int*   tk_idx   = (int*)(tk_val + (size_t)M * KTOP);  // M*KTOP
    float* p        = (float*)(tk_idx + (size_t)M * KTOP);// B*LSEQ
    float* pooled   = p + BATCH * LSEQ;                   // B*D
    float* y        = pooled + BATCH * D;                 // B*D
    float* z        = y + BATCH * D;                      // B*DOUT

    hipLaunchKernelGGL(topk_kernel, dim3(M), dim3(256), 0, stream,
                       attention, tk_idx, tk_val);
    hipLaunchKernelGGL(gemm_kernel, dim3(D / 64, M / 64, 2), dim3(256), 0, stream,
                       hidden, W_src, b_src, feat_src, W_dst, b_dst, feat_dst);
    hipLaunchKernelGGL(gat_kernel, dim3(M), dim3(256), 0, stream,
                       feat_src, feat_dst, attn_vec, hidden, gat_bias,
                       gate_W, gate_b, tk_idx, tk_val, h, gate);
    hipLaunchKernelGGL(gatesm_kernel, dim3(BATCH), dim3(256), 0, stream,
                       gate, p, pooled, z);
    hipLaunchKernelGGL(pool_kernel, dim3(D / 256, LSEQ / 64, BATCH), dim3(256), 0, stream,
                       h, p, pooled);
    hipLaunchKernelGGL(ln1_kernel, dim3(BATCH), dim3(256), 0, stream,
                       pooled, ln_g, ln_b, y);
    hipLaunchKernelGGL(fc_kernel, dim3(DOUT / 64, D / 256, BATCH), dim3(256), 0, stream,
                       y, fc_W, z);
    hipLaunchKernelGGL(ln2_kernel, dim3(BATCH), dim3(384), 0, stream,
                       z, fc_b, ln2_g, ln2_b, out);
}

// Round 3
// 275.191 us; speedup vs baseline: 1.4295x; 1.1644x over previous
//
#include <hip/hip_runtime.h>
#include <math.h>

#define D 768
#define DOUT 384
#define LSEQ 512
#define BATCH 4
#define KTOP 51
#define EPS 1e-5f

typedef unsigned short ushort_t;
typedef __bf16 bf16x8 __attribute__((ext_vector_type(8)));
typedef float f32x4 __attribute__((ext_vector_type(4)));

// global->LDS direct DMA, 16B per lane. LDS dest is wave-uniform base + lane*16.
#define GLOAD16(gp, lp)                                                        \
    __builtin_amdgcn_global_load_lds(                                          \
        (const __attribute__((address_space(1))) unsigned int*)(gp),           \
        (__attribute__((address_space(3))) unsigned int*)(lp), 16, 0, 0)

// fp32 -> bf16 round-to-nearest-even (inputs are finite; NaN path not needed)
__device__ __forceinline__ ushort_t f2bf(float f) {
    unsigned int u = __builtin_bit_cast(unsigned int, f);
    u = (u + 0x7FFFu + ((u >> 16) & 1u)) >> 16;
    return (ushort_t)u;
}

// ---------------------------------------------------------------------------
// Top-K selection: one block per attention row. Rank-based selection exactly
// matches jax.lax.top_k tie rule (lower index wins); only the SET of indices
// matters downstream (softmax over k + sum over k are order-invariant).
// ---------------------------------------------------------------------------
__global__ __launch_bounds__(256) void topk_kernel(const float* __restrict__ attn,
                                                   int* __restrict__ tk_idx,
                                                   float* __restrict__ tk_val) {
    const int row = blockIdx.x;                 // b*L + l
    const float* a = attn + (size_t)row * LSEQ;
    __shared__ float vals[LSEQ];
    __shared__ int cnt;
    const int tid = threadIdx.x;
    vals[tid] = a[tid];
    vals[tid + 256] = a[tid + 256];
    if (tid == 0) cnt = 0;
    __syncthreads();
#pragma unroll
    for (int e0 = 0; e0 < 2; ++e0) {
        const int e = tid + e0 * 256;
        const float v = vals[e];
        int rank = 0;
#pragma unroll 8
        for (int j = 0; j < LSEQ; ++j) {
            const float u = vals[j];
            rank += (u > v) || (u == v && j < e);
        }
        if (rank < KTOP) {
            const int slot = atomicAdd(&cnt, 1);
            tk_idx[row * KTOP + slot] = e;
            tk_val[row * KTOP + slot] = v;
        }
    }
}

// ---------------------------------------------------------------------------
// Prep 1: hidden fp32 (2048x768) -> bf16 row-major. 4 elems/thread.
// ---------------------------------------------------------------------------
__global__ __launch_bounds__(256) void cvt_hidden_kernel(const float* __restrict__ x,
                                                         ushort_t* __restrict__ xb) {
    const int i = (blockIdx.x * 256 + threadIdx.x) * 4;
    const float4 v = *(const float4*)(x + i);
    ushort4 o;
    o.x = f2bf(v.x); o.y = f2bf(v.y); o.z = f2bf(v.z); o.w = f2bf(v.w);
    *(ushort4*)(xb + i) = o;
}

// ---------------------------------------------------------------------------
// Prep 2: W fp32 [k][n] -> WT bf16 [n][k], 32x32 LDS tile transpose.
// grid (24, 24, 2): z selects W_src->WT0 / W_dst->WT1.
// ---------------------------------------------------------------------------
__global__ __launch_bounds__(256) void cvt_w_kernel(const float* __restrict__ W0,
                                                    const float* __restrict__ W1,
                                                    ushort_t* __restrict__ WT0,
                                                    ushort_t* __restrict__ WT1) {
    const float* W = blockIdx.z ? W1 : W0;
    ushort_t* WT = blockIdx.z ? WT1 : WT0;
    __shared__ float tile[32][33];
    const int tid = threadIdx.x;
    const int kbase = blockIdx.y * 32;
    const int nbase = blockIdx.x * 32;
    const int r = tid >> 3, c4 = (tid & 7) * 4;

    const float4 v = *(const float4*)(W + (size_t)(kbase + r) * D + nbase + c4);
    tile[r][c4 + 0] = v.x; tile[r][c4 + 1] = v.y; tile[r][c4 + 2] = v.z; tile[r][c4 + 3] = v.w;
    __syncthreads();
    // write WT[n][k]: thread writes row n=r, k cols c4..c4+3 = tile[c4+i][r]
    ushort4 o;
    o.x = f2bf(tile[c4 + 0][r]); o.y = f2bf(tile[c4 + 1][r]);
    o.z = f2bf(tile[c4 + 2][r]); o.w = f2bf(tile[c4 + 3][r]);
    *(ushort4*)(WT + (size_t)(nbase + r) * D + kbase + c4) = o;
}

// ---------------------------------------------------------------------------
// bf16 MFMA GEMM: C = A(2048x768) @ W(768x768) + bias (fp32 out).
// BM=BN=128, BK=32, 256 threads / 4 waves, each wave one 64x64 quadrant
// (4x4 frags of mfma_f32_16x16x32_bf16). global_load_lds width-16 staging.
// A staged [128m][32k] contiguous; B staged from WT as [128n][32k] contiguous.
// ---------------------------------------------------------------------------
__global__ __launch_bounds__(256) void mfma_gemm_kernel(const ushort_t* __restrict__ Ah,
                                                        const ushort_t* __restrict__ WT0,
                                                        const float* __restrict__ b0,
                                                        float* __restrict__ C0,
                                                        const ushort_t* __restrict__ WT1,
                                                        const float* __restrict__ b1,
                                                        float* __restrict__ C1) {
    const ushort_t* WT = blockIdx.z ? WT1 : WT0;
    const float* bias = blockIdx.z ? b1 : b0;
    float* C = blockIdx.z ? C1 : C0;

    __shared__ ushort_t As[128 * 32];   // [m][k], no padding (global_load_lds)
    __shared__ ushort_t Bs[128 * 32];   // [n][k]

    const int tid = threadIdx.x;
    const int lane = tid & 63;
    const int wave = tid >> 6;
    const int quad = lane >> 4;
    const int m15 = lane & 15;
    const int qRow = (wave & 1) * 64;
    const int qCol = (wave >> 1) * 64;

    const int rowBase = blockIdx.y * 128;
    const int colBase = blockIdx.x * 128;

    // staging: thread covers tile elems e0 = tid*8 and e0+2048 (of 128*32=4096)
    const int e0 = tid * 8;
    const int r0 = e0 >> 5;         // 0..63
    const int c0 = e0 & 31;         // {0,8,16,24}
    const ushort_t* Abase = Ah + (size_t)rowBase * D;
    const ushort_t* Bbase = WT + (size_t)colBase * D;

    f32x4 acc[4][4] = {};

    for (int kk = 0; kk < D; kk += 32) {
        __syncthreads();            // previous iter's LDS reads complete
        GLOAD16(Abase + (size_t)r0 * D + kk + c0,        &As[e0]);
        GLOAD16(Abase + (size_t)(r0 + 64) * D + kk + c0, &As[e0 + 2048]);
        GLOAD16(Bbase + (size_t)r0 * D + kk + c0,        &Bs[e0]);
        GLOAD16(Bbase + (size_t)(r0 + 64) * D + kk + c0, &Bs[e0 + 2048]);
        __syncthreads();            // vmcnt(0) drain -> tiles resident

        bf16x8 a[4], b[4];
#pragma unroll
        for (int i = 0; i < 4; ++i)
            a[i] = *(const bf16x8*)&As[(qRow + i * 16 + m15) * 32 + quad * 8];
#pragma unroll
        for (int j = 0; j < 4; ++j)
            b[j] = *(const bf16x8*)&Bs[(qCol + j * 16 + m15) * 32 + quad * 8];
#pragma unroll
        for (int i = 0; i < 4; ++i)
#pragma unroll
            for (int j = 0; j < 4; ++j)
                acc[i][j] = __builtin_amdgcn_mfma_f32_16x16x32_bf16(a[i], b[j], acc[i][j], 0, 0, 0);
    }

    // epilogue: C/D layout col=lane&15, row=quad*4+reg
#pragma unroll
    for (int j = 0; j < 4; ++j) {
        const int col = colBase + qCol + j * 16 + m15;
        const float bv = bias[col];
#pragma unroll
        for (int i = 0; i < 4; ++i) {
            float* Cp = C + (size_t)(rowBase + qRow + i * 16 + quad * 4) * D + col;
#pragma unroll
            for (int r = 0; r < 4; ++r)
                Cp[(size_t)r * D] = acc[i][j][r] + bv;
        }
    }
}

// ---------------------------------------------------------------------------
// GAT: scores -> softmax over K -> aggregate -> residual + leaky -> gate dot.
// One block of 256 threads (4 waves) per (b,l).
// ---------------------------------------------------------------------------
__global__ __launch_bounds__(256) void gat_kernel(const float* __restrict__ feat_src,
                                                  const float* __restrict__ feat_dst,
                                                  const float* __restrict__ attn_vec,
                                                  const float* __restrict__ hidden,
                                                  const float* __restrict__ gat_bias,
                                                  const float* __restrict__ gate_W,
                                                  const float* __restrict__ gate_b,
                                                  const int* __restrict__ tk_idx,
                                                  const float* __restrict__ tk_val,
                                                  float* __restrict__ h_out,
                                                  float* __restrict__ gate_out) {
    const int row = blockIdx.x;     // b*L + l
    const int b = row >> 9;
    const int tid = threadIdx.x;
    const int lane = tid & 63;
    const int wave = tid >> 6;

    __shared__ float fd[D];
    __shared__ float av[D];
    __shared__ float sc[KTOP];
    __shared__ int kid[KTOP];
    __shared__ float red[256];

    for (int d = tid; d < D; d += 256) {
        fd[d] = feat_dst[(size_t)row * D + d];
        av[d] = attn_vec[d];
    }
    if (tid < KTOP) kid[tid] = tk_idx[row * KTOP + tid];
    __syncthreads();

    for (int k = wave; k < KTOP; k += 4) {
        const float* g = feat_src + ((size_t)(b << 9) + kid[k]) * D;
        float s = 0.f;
        for (int d = lane; d < D; d += 64) {
            float x = g[d] + fd[d];
            x = x > 0.f ? x : 0.2f * x;
            s += x * av[d];
        }
#pragma unroll
        for (int off = 32; off > 0; off >>= 1) s += __shfl_down(s, off);
        if (lane == 0) {
            const float v = tk_val[row * KTOP + k];
            sc[k] = (v > 0.f) ? s : -1e9f;
        }
    }
    __syncthreads();

    if (wave == 0) {
        float s = (lane < KTOP) ? sc[lane] : -3.0e38f;
        float m = s;
#pragma unroll
        for (int off = 32; off > 0; off >>= 1) m = fmaxf(m, __shfl_xor(m, off));
        float e = (lane < KTOP) ? __expf(s - m) : 0.f;
        float sum = e;
#pragma unroll
        for (int off = 32; off > 0; off >>= 1) sum += __shfl_xor(sum, off);
        if (lane < KTOP) sc[lane] = e / sum;
    }
    __syncthreads();

    float gpart = 0.f;
    for (int d = tid; d < D; d += 256) {
        float acc = 0.f;
        for (int k = 0; k < KTOP; ++k) {
            const float* g = feat_src + ((size_t)(b << 9) + kid[k]) * D;
            acc += sc[k] * g[d];
        }
        float hv = acc + hidden[(size_t)row * D + d] + gat_bias[d];
        hv = hv > 0.f ? hv : 0.01f * hv;
        h_out[(size_t)row * D + d] = hv;
        gpart += hv * gate_W[d];
    }
    red[tid] = gpart;
    __syncthreads();
    for (int s = 128; s > 0; s >>= 1) {
        if (tid < s) red[tid] += red[tid + s];
        __syncthreads();
    }
    if (tid == 0) gate_out[row] = red[0] + gate_b[0];
}

// ---------------------------------------------------------------------------
// Final stage (split for parallelism, R1).
// ---------------------------------------------------------------------------
__global__ __launch_bounds__(256) void gatesm_kernel(const float* __restrict__ gate,
                                                     float* __restrict__ p,
                                                     float* __restrict__ pooled,
                                                     float* __restrict__ z) {
    const int b = blockIdx.x;
    const int tid = threadIdx.x;
    __shared__ float red[256];

    const float g0 = gate[b * LSEQ + tid];
    const float g1 = gate[b * LSEQ + tid + 256];
    red[tid] = fmaxf(g0, g1);
    __syncthreads();
    for (int s = 128; s > 0; s >>= 1) { if (tid < s) red[tid] = fmaxf(red[tid], red[tid + s]); __syncthreads(); }
    const float m = red[0];
    __syncthreads();
    const float e0 = __expf(g0 - m), e1 = __expf(g1 - m);
    red[tid] = e0 + e1;
    __syncthreads();
    for (int s = 128; s > 0; s >>= 1) { if (tid < s) red[tid] += red[tid + s]; __syncthreads(); }
    const float inv = 1.f / red[0];
    p[b * LSEQ + tid] = e0 * inv;
    p[b * LSEQ + tid + 256] = e1 * inv;

    for (int d = tid; d < D; d += 256) pooled[b * D + d] = 0.f;
    if (tid < 128) { z[b * DOUT + tid] = 0.f; z[b * DOUT + tid + 128] = 0.f; z[b * DOUT + tid + 256] = 0.f; }
}

__global__ __launch_bounds__(256) void pool_kernel(const float* __restrict__ h,
                                                   const float* __restrict__ p,
                                                   float* __restrict__ pooled) {
    const int b = blockIdx.z;
    const int lbase = blockIdx.y * 64;
    const int d = blockIdx.x * 256 + threadIdx.x;
    const int tid = threadIdx.x;

    __shared__ float ps[64];
    if (tid < 64) ps[tid] = p[b * LSEQ + lbase + tid];
    __syncthreads();

    const float* hb = h + ((size_t)(b * LSEQ + lbase)) * D + d;
    float acc = 0.f;
#pragma unroll 8
    for (int l = 0; l < 64; ++l) {
        acc += ps[l] * hb[(size_t)l * D];
    }
    atomicAdd(&pooled[b * D + d], acc);
}

__global__ __launch_bounds__(256) void ln1_kernel(const float* __restrict__ pooled,
                                                  const float* __restrict__ ln_g,
                                                  const float* __restrict__ ln_b,
                                                  float* __restrict__ y) {
    const int b = blockIdx.x;
    const int tid = threadIdx.x;
    __shared__ float red[256];

    float v[3];
#pragma unroll
    for (int i = 0; i < 3; ++i) v[i] = fmaxf(pooled[b * D + tid + i * 256], 0.f);

    red[tid] = v[0] + v[1] + v[2];
    __syncthreads();
    for (int s = 128; s > 0; s >>= 1) { if (tid < s) red[tid] += red[tid + s]; __syncthreads(); }
    const float mu = red[0] / (float)D;
    __syncthreads();
    float vs = 0.f;
#pragma unroll
    for (int i = 0; i < 3; ++i) { const float dd = v[i] - mu; vs += dd * dd; }
    red[tid] = vs;
    __syncthreads();
    for (int s = 128; s > 0; s >>= 1) { if (tid < s) red[tid] += red[tid + s]; __syncthreads(); }
    const float rstd = rsqrtf(red[0] / (float)D + EPS);
#pragma unroll
    for (int i = 0; i < 3; ++i) {
        const int d = tid + i * 256;
        y[b * D + d] = (v[i] - mu) * rstd * ln_g[d] + ln_b[d];
    }
}

__global__ __launch_bounds__(256) void fc_kernel(const float* __restrict__ y,
                                                 const float* __restrict__ fc_W,
                                                 float* __restrict__ z) {
    const int b = blockIdx.z;
    const int dbase = blockIdx.y * 256;
    const int jbase = blockIdx.x * 64;
    const int tid = threadIdx.x;
    const int jt = tid & 63;
    const int sub = tid >> 6;

    __shared__ float ys[256];
    __shared__ float part[4][64];
    ys[tid] = y[b * D + dbase + tid];
    __syncthreads();

    const float* W = fc_W + (size_t)(dbase + sub * 64) * DOUT + jbase + jt;
    const float* yy = ys + sub * 64;
    float acc = 0.f;
#pragma unroll 8
    for (int i = 0; i < 64; ++i) {
        acc += yy[i] * W[(size_t)i * DOUT];
    }
    part[sub][jt] = acc;
    __syncthreads();
    if (sub == 0) {
        const float tot = part[0][jt] + part[1][jt] + part[2][jt] + part[3][jt];
        atomicAdd(&z[b * DOUT + jbase + jt], tot);
    }
}

__global__ __launch_bounds__(384) void ln2_kernel(const float* __restrict__ z,
                                                  const float* __restrict__ fc_b,
                                                  const float* __restrict__ ln2_g,
                                                  const float* __restrict__ ln2_b,
                                                  float* __restrict__ out) {
    const int b = blockIdx.x;
    const int tid = threadIdx.x;
    const int lane = tid & 63;
    const int wave = tid >> 6;
    __shared__ float wred[6];

    const float v = z[b * DOUT + tid] + fc_b[tid];

    float s = v;
#pragma unroll
    for (int off = 32; off > 0; off >>= 1) s += __shfl_xor(s, off);
    if (lane == 0) wred[wave] = s;
    __syncthreads();
    float mu = 0.f;
#pragma unroll
    for (int w = 0; w < 6; ++w) mu += wred[w];
    mu /= (float)DOUT;
    __syncthreads();

    const float dd = v - mu;
    float s2 = dd * dd;
#pragma unroll
    for (int off = 32; off > 0; off >>= 1) s2 += __shfl_xor(s2, off);
    if (lane == 0) wred[wave] = s2;
    __syncthreads();
    float var = 0.f;
#pragma unroll
    for (int w = 0; w < 6; ++w) var += wred[w];
    const float rstd = rsqrtf(var / (float)DOUT + EPS);

    out[b * DOUT + tid] = dd * rstd * ln2_g[tid] + ln2_b[tid];
}

extern "C" void kernel_launch(void* const* d_in, const int* in_sizes, int n_in,
                              void* d_out, int out_size, void* d_ws, size_t ws_size,
                              hipStream_t stream) {
    const float* hidden   = (const float*)d_in[0];   // (4,512,768)
    const float* attention= (const float*)d_in[1];   // (4,512,512)
    const float* W_src    = (const float*)d_in[2];
    const float* b_src    = (const float*)d_in[3];
    const float* W_dst    = (const float*)d_in[4];
    const float* b_dst    = (const float*)d_in[5];
    const float* attn_vec = (const float*)d_in[6];
    const float* gat_bias = (const float*)d_in[7];
    const float* gate_W   = (const float*)d_in[8];
    const float* gate_b   = (const float*)d_in[9];
    const float* ln_g     = (const float*)d_in[10];
    const float* ln_b     = (const float*)d_in[11];
    const float* fc_W     = (const float*)d_in[12];
    const float* fc_b     = (const float*)d_in[13];
    const float* ln2_g    = (const float*)d_in[14];
    const float* ln2_b    = (const float*)d_in[15];
    float* out = (float*)d_out;

    const int M = BATCH * LSEQ;           // 2048
    float* feat_src = (float*)d_ws;                       // M*D
    float* feat_dst = feat_src + (size_t)M * D;           // M*D
    float* h        = feat_dst + (size_t)M * D;           // M*D
    float* gate     = h + (size_t)M * D;                  // M
    float* tk_val   = gate + M;                           // M*KTOP (104448, /8 ok)
    int*   tk_idx   = (int*)(tk_val + (size_t)M * KTOP);  // M*KTOP
    float* p        = (float*)(tk_idx + (size_t)M * KTOP);// B*LSEQ
    float* pooled   = p + BATCH * LSEQ;                   // B*D
    float* y        = pooled + BATCH * D;                 // B*D
    float* z        = y + BATCH * D;                      // B*DOUT (1536, /8 ok)
    ushort_t* Ah    = (ushort_t*)(z + BATCH * DOUT);      // M*D bf16
    ushort_t* WT0   = Ah + (size_t)M * D;                 // D*D bf16 [n][k]
    ushort_t* WT1   = WT0 + (size_t)D * D;                // D*D bf16 [n][k]

    hipLaunchKernelGGL(topk_kernel, dim3(M), dim3(256), 0, stream,
                       attention, tk_idx, tk_val);
    hipLaunchKernelGGL(cvt_hidden_kernel, dim3((M * D) / 1024), dim3(256), 0, stream,
                       hidden, Ah);
    hipLaunchKernelGGL(cvt_w_kernel, dim3(D / 32, D / 32, 2), dim3(256), 0, stream,
                       W_src, W_dst, WT0, WT1);
    hipLaunchKernelGGL(mfma_gemm_kernel, dim3(D / 128, M / 128, 2), dim3(256), 0, stream,
                       Ah, WT0, b_src, feat_src, WT1, b_dst, feat_dst);
    hipLaunchKernelGGL(gat_kernel, dim3(M), dim3(256), 0, stream,
                       feat_src, feat_dst, attn_vec, hidden, gat_bias,
                       gate_W, gate_b, tk_idx, tk_val, h, gate);
    hipLaunchKernelGGL(gatesm_kernel, dim3(BATCH), dim3(256), 0, stream,
                       gate, p, pooled, z);
    hipLaunchKernelGGL(pool_kernel, dim3(D / 256, LSEQ / 64, BATCH), dim3(256), 0, stream,
                       h, p, pooled);
    hipLaunchKernelGGL(ln1_kernel, dim3(BATCH), dim3(256), 0, stream,
                       pooled, ln_g, ln_b, y);
    hipLaunchKernelGGL(fc_kernel, dim3(DOUT / 64, D / 256, BATCH), dim3(256), 0, stream,
                       y, fc_W, z);
    hipLaunchKernelGGL(ln2_kernel, dim3(BATCH), dim3(384), 0, stream,
                       z, fc_b, ln2_g, ln2_b, out);
}